// Round 13
// baseline (932.775 us; speedup 1.0000x reference)
//
#include <hip/hip_runtime.h>
#include <hip/hip_bf16.h>
#include <math.h>

#define NN 3600
#define HIMG 300
#define WIMG 300
#define NHP 60
#define NCT 57   // ceil(3600/64) column tiles for adj

typedef __attribute__((ext_vector_type(8))) short bf16x8;
typedef __attribute__((ext_vector_type(4))) float f32x4;

__device__ __forceinline__ float bf2f(unsigned short u) {
  union { unsigned int i; float f; } v; v.i = ((unsigned int)u) << 16; return v.f;
}
__device__ __forceinline__ float ldE(const void* p, long i, int md) {
  return md ? bf2f(((const unsigned short*)p)[i]) : ((const float*)p)[i];
}
__device__ __forceinline__ unsigned short f2bf(float f) {
  __hip_bfloat16 h = __float2bfloat16(f);
  return *(unsigned short*)&h;
}

// flag[0] = detected mode, flag[1] = 0 (f32-mode const for ws buffers)
__global__ __launch_bounds__(256) void detect_mode(
    const unsigned short* __restrict__ x, int* __restrict__ flag) {
  __shared__ int bad;
  if (threadIdx.x == 0) bad = 0;
  __syncthreads();
  int b = 0;
  for (int i = threadIdx.x; i < 8192; i += 256) {
    int e = (x[i] >> 7) & 0xFF;
    if (e >= 0x90) b = 1;
  }
  if (b) atomicOr(&bad, 1);
  __syncthreads();
  if (threadIdx.x == 0) {
    flag[0] = bad ? 0 : 1;
    flag[1] = 0;
  }
}

// ---------------- w[o][k] -> wT[k][o] (f32) ----------------
__global__ __launch_bounds__(256) void wtrans(
    const void* __restrict__ w, float* __restrict__ wT, const int* __restrict__ mode) {
  const int md = *mode;
  __shared__ float t[32][33];
  const int k0 = blockIdx.x * 32, o0 = blockIdx.y * 32;
  const int tx = threadIdx.x & 31, ty = threadIdx.x >> 5;
#pragma unroll
  for (int s = 0; s < 32; s += 8)
    t[ty + s][tx] = ldE(w, (long)(o0 + ty + s) * 6400 + k0 + tx, md);
  __syncthreads();
#pragma unroll
  for (int s = 0; s < 32; s += 8)
    wT[(size_t)(k0 + ty + s) * 256 + o0 + tx] = t[tx][ty + s];
}

// -------- weight convert+transpose bf16, L/R fused via z: src [K][N] -> dst [N][K] --------
__global__ __launch_bounds__(256) void wconvT2(
    const void* __restrict__ srcL, const void* __restrict__ srcR,
    unsigned short* __restrict__ dstL, unsigned short* __restrict__ dstR,
    int Kd, int Nd, const int* __restrict__ mode) {
  const int md = *mode;
  const void* src = blockIdx.z ? srcR : srcL;
  unsigned short* dst = blockIdx.z ? dstR : dstL;
  __shared__ float t[32][33];
  const int k0 = blockIdx.x * 32, n0 = blockIdx.y * 32;
  const int tx = threadIdx.x & 31, ty = threadIdx.x >> 5;
#pragma unroll
  for (int s = 0; s < 32; s += 8)
    t[ty + s][tx] = ldE(src, (long)(k0 + ty + s) * Nd + n0 + tx, md);
  __syncthreads();
#pragma unroll
  for (int s = 0; s < 32; s += 8)
    dst[(size_t)(n0 + ty + s) * Kd + k0 + tx] = f2bf(t[tx][ty + s]);
}

// -------- flat f32 -> bf16 --------
__global__ __launch_bounds__(256) void cvt_bf16(
    const float* __restrict__ src, unsigned short* __restrict__ dst, long n4) {
  for (long i = (long)blockIdx.x * 256 + threadIdx.x; i < n4; i += (long)gridDim.x * 256) {
    float4 v = *(const float4*)(src + i * 4);
    ushort4 o;
    o.x = f2bf(v.x); o.y = f2bf(v.y); o.z = f2bf(v.z); o.w = f2bf(v.w);
    *(ushort4*)(dst + i * 4) = o;
  }
}

// ---------------- im2col (one K-half) ----------------
__global__ __launch_bounds__(256) void im2col(
    const void* __restrict__ x, float* __restrict__ a2, int h, const int* __restrict__ mode) {
  const int md = *mode;
  const int total = NN * 3200;
  for (int i = blockIdx.x * 256 + threadIdx.x; i < total; i += gridDim.x * 256) {
    int n = i / 3200, kl = i - n * 3200;
    int k = h * 3200 + kl;
    int c = k / 25, q = k - c * 25;
    int ki = q / 5, li = q - ki * 5;
    int ni = n / NHP, nj = n - ni * NHP;
    a2[i] = ldE(x, (long)c * (HIMG * WIMG) + (5 * ni + ki) * WIMG + 5 * nj + li, md);
  }
}

// ======== 128x64 f32 partial GEMM, 8x4/thread, reg-prefetch pipelined (conv) ========
__global__ __launch_bounds__(256) void gemm_f84(
    const float* __restrict__ A, const float* __restrict__ B, long boff,
    float* __restrict__ part, int M, int lda, int kchunk, int ldb) {
  __shared__ float As[16][136];
  __shared__ float Bs[16][68];
  const int m0 = blockIdx.y * 128, n0 = blockIdx.x * 64;
  const int z = blockIdx.z;
  const int tid = threadIdx.x;
  const int tr = tid >> 4, tc = tid & 15;
  const int ar = tid >> 1, akq = tid & 1;
  const int bkr = tid >> 4, bnc = tid & 15;
  const int arow = m0 + ar;
  float acc[8][4] = {};

  const int kb = z * kchunk, ke = kb + kchunk;
  float4 pa0 = make_float4(0.f, 0.f, 0.f, 0.f), pa1 = pa0, pb;
  if (arow < M) {
    const float* ap = A + (size_t)arow * lda + kb + akq * 8;
    pa0 = *(const float4*)ap;
    pa1 = *(const float4*)(ap + 4);
  }
  pb = *(const float4*)(B + (size_t)(kb + bkr) * ldb + boff + n0 + bnc * 4);

  for (int k0 = kb; k0 < ke; k0 += 16) {
    __syncthreads();
    As[akq * 8 + 0][ar] = pa0.x;
    As[akq * 8 + 1][ar] = pa0.y;
    As[akq * 8 + 2][ar] = pa0.z;
    As[akq * 8 + 3][ar] = pa0.w;
    As[akq * 8 + 4][ar] = pa1.x;
    As[akq * 8 + 5][ar] = pa1.y;
    As[akq * 8 + 6][ar] = pa1.z;
    As[akq * 8 + 7][ar] = pa1.w;
    Bs[bkr][bnc * 4 + 0] = pb.x;
    Bs[bkr][bnc * 4 + 1] = pb.y;
    Bs[bkr][bnc * 4 + 2] = pb.z;
    Bs[bkr][bnc * 4 + 3] = pb.w;
    __syncthreads();
    if (k0 + 16 < ke) {
      if (arow < M) {
        const float* ap = A + (size_t)arow * lda + (k0 + 16) + akq * 8;
        pa0 = *(const float4*)ap;
        pa1 = *(const float4*)(ap + 4);
      }
      pb = *(const float4*)(B + (size_t)(k0 + 16 + bkr) * ldb + boff + n0 + bnc * 4);
    }
#pragma unroll
    for (int kk = 0; kk < 16; ++kk) {
      float4 a0 = *(const float4*)&As[kk][tr * 8];
      float4 a1 = *(const float4*)&As[kk][tr * 8 + 4];
      float4 bv = *(const float4*)&Bs[kk][tc * 4];
      float a[8] = {a0.x, a0.y, a0.z, a0.w, a1.x, a1.y, a1.z, a1.w};
      float b[4] = {bv.x, bv.y, bv.z, bv.w};
#pragma unroll
      for (int i = 0; i < 8; ++i)
#pragma unroll
        for (int j = 0; j < 4; ++j) acc[i][j] = fmaf(a[i], b[j], acc[i][j]);
    }
  }
#pragma unroll
  for (int i = 0; i < 8; ++i) {
    int row = m0 + tr * 8 + i;
    if (row < M) {
#pragma unroll
      for (int j = 0; j < 4; ++j)
        part[((size_t)z * M + row) * 256 + n0 + tc * 4 + j] = acc[i][j];
    }
  }
}

// ================= unified 64x64 f32 GEMM (fc2 / narrow path) =================
template <int STORE, int ACT>
__global__ __launch_bounds__(256) void gemm_u(
    const float* __restrict__ A, const void* __restrict__ B0, const void* __restrict__ B1,
    long boff, const void* __restrict__ bias0, const void* __restrict__ bias1, long biasoff,
    float* __restrict__ C0, float* __restrict__ C1, float* __restrict__ part, int cld,
    int M, int lda, int kchunk, int KS, int ldb, const int* __restrict__ mode) {
  const int md = *mode;
  const int z = blockIdx.z;
  const int pair = z / KS, ks = z - pair * KS;
  const void* B = pair ? B1 : B0;
  const void* bias = pair ? bias1 : bias0;
  float* C = pair ? C1 : C0;
  __shared__ float As[16][68];
  __shared__ float Bs[16][68];
  const int m0 = blockIdx.y * 64, n0 = blockIdx.x * 64;
  const int tid = threadIdx.x;
  const int tr = tid >> 4, tc = tid & 15;
  const int ar = tid >> 2, akq = tid & 3;
  const int bkr = tid >> 4, bnc = tid & 15;
  const int arow = m0 + ar;
  float acc[4][4] = {};

  const int kb = ks * kchunk, ke = kb + kchunk;
  for (int k0 = kb; k0 < ke; k0 += 16) {
    __syncthreads();
    {
      float4 v = make_float4(0.f, 0.f, 0.f, 0.f);
      if (arow < M) v = *(const float4*)(A + (size_t)arow * lda + k0 + akq * 4);
      As[akq * 4 + 0][ar] = v.x;
      As[akq * 4 + 1][ar] = v.y;
      As[akq * 4 + 2][ar] = v.z;
      As[akq * 4 + 3][ar] = v.w;
    }
    {
      long bidx = (long)(k0 + bkr) * ldb + boff + n0 + bnc * 4;
      if (md) {
        ushort4 u = *(const ushort4*)((const unsigned short*)B + bidx);
        Bs[bkr][bnc * 4 + 0] = bf2f(u.x);
        Bs[bkr][bnc * 4 + 1] = bf2f(u.y);
        Bs[bkr][bnc * 4 + 2] = bf2f(u.z);
        Bs[bkr][bnc * 4 + 3] = bf2f(u.w);
      } else {
        float4 v = *(const float4*)((const float*)B + bidx);
        Bs[bkr][bnc * 4 + 0] = v.x;
        Bs[bkr][bnc * 4 + 1] = v.y;
        Bs[bkr][bnc * 4 + 2] = v.z;
        Bs[bkr][bnc * 4 + 3] = v.w;
      }
    }
    __syncthreads();
#pragma unroll
    for (int kk = 0; kk < 16; ++kk) {
      float4 av = *(const float4*)&As[kk][tr * 4];
      float4 bv = *(const float4*)&Bs[kk][tc * 4];
      float a[4] = {av.x, av.y, av.z, av.w};
      float b[4] = {bv.x, bv.y, bv.z, bv.w};
#pragma unroll
      for (int i = 0; i < 4; ++i)
#pragma unroll
        for (int j = 0; j < 4; ++j) acc[i][j] = fmaf(a[i], b[j], acc[i][j]);
    }
  }
#pragma unroll
  for (int i = 0; i < 4; ++i) {
    int row = m0 + tr * 4 + i;
    if (row < M) {
#pragma unroll
      for (int j = 0; j < 4; ++j) {
        int col = n0 + tc * 4 + j;
        if (STORE == 2) {
          part[((size_t)z * M + row) * cld + col] = acc[i][j];
        } else if (STORE == 1) {
          C[(size_t)row * cld + col] += acc[i][j];
        } else {
          float v = acc[i][j] + ldE(bias, biasoff + col, md);
          if (ACT == 1) v = fmaxf(v, 0.f);
          C[(size_t)row * cld + col] = v;
        }
      }
    }
  }
}

// ================= MFMA bf16 GEMM, reg-prefetch pipelined =================
template <int STORE>
__global__ __launch_bounds__(256) void gemm_mf(
    const unsigned short* __restrict__ A,
    const unsigned short* __restrict__ B0, const unsigned short* __restrict__ B1,
    const void* __restrict__ bias0, const void* __restrict__ bias1,
    float* __restrict__ C0, float* __restrict__ C1, float* __restrict__ part, int cld,
    int M, int K, int kchunk, int KS, const int* __restrict__ mode) {
  const int md = *mode;
  const int z = blockIdx.z;
  const int pair = z / KS, ks = z - pair * KS;
  const unsigned short* B = pair ? B1 : B0;
  const void* bias = pair ? bias1 : bias0;
  float* C = pair ? C1 : C0;

  __shared__ __align__(16) unsigned short Al[128][40];
  __shared__ __align__(16) unsigned short Bl[128][40];
  const int m0 = blockIdx.y * 128, n0 = blockIdx.x * 128;
  const int tid = threadIdx.x;
  const int lane = tid & 63, w = tid >> 6;
  const int wr = (w >> 1) * 64, wc = (w & 1) * 64;
  const int frow = lane & 15, fk = (lane >> 4) * 8;
  const int sr0 = tid >> 2, skc0 = (tid & 3) << 3;
  const int sr1 = (tid + 256) >> 2, skc1 = ((tid + 256) & 3) << 3;

  f32x4 acc[4][4];
#pragma unroll
  for (int i = 0; i < 4; ++i)
#pragma unroll
    for (int j = 0; j < 4; ++j) acc[i][j] = (f32x4){0.f, 0.f, 0.f, 0.f};

  const int kb0 = ks * kchunk, ke = kb0 + kchunk;
  uint4 qa0 = make_uint4(0, 0, 0, 0), qa1 = qa0, qb0, qb1;
  {
    int gr0 = m0 + sr0, gr1 = m0 + sr1;
    if (gr0 < M) qa0 = *(const uint4*)(A + (size_t)gr0 * K + kb0 + skc0);
    if (gr1 < M) qa1 = *(const uint4*)(A + (size_t)gr1 * K + kb0 + skc1);
    qb0 = *(const uint4*)(B + (size_t)(n0 + sr0) * K + kb0 + skc0);
    qb1 = *(const uint4*)(B + (size_t)(n0 + sr1) * K + kb0 + skc1);
  }

  for (int kb = kb0; kb < ke; kb += 32) {
    __syncthreads();
    *(uint4*)&Al[sr0][skc0] = qa0;
    *(uint4*)&Al[sr1][skc1] = qa1;
    *(uint4*)&Bl[sr0][skc0] = qb0;
    *(uint4*)&Bl[sr1][skc1] = qb1;
    __syncthreads();
    if (kb + 32 < ke) {
      int kn = kb + 32;
      int gr0 = m0 + sr0, gr1 = m0 + sr1;
      qa0 = make_uint4(0, 0, 0, 0); qa1 = qa0;
      if (gr0 < M) qa0 = *(const uint4*)(A + (size_t)gr0 * K + kn + skc0);
      if (gr1 < M) qa1 = *(const uint4*)(A + (size_t)gr1 * K + kn + skc1);
      qb0 = *(const uint4*)(B + (size_t)(n0 + sr0) * K + kn + skc0);
      qb1 = *(const uint4*)(B + (size_t)(n0 + sr1) * K + kn + skc1);
    }

    bf16x8 af[4], bfr[4];
#pragma unroll
    for (int rt = 0; rt < 4; ++rt)
      af[rt] = *(const bf16x8*)&Al[wr + rt * 16 + frow][fk];
#pragma unroll
    for (int ct = 0; ct < 4; ++ct)
      bfr[ct] = *(const bf16x8*)&Bl[wc + ct * 16 + frow][fk];
#pragma unroll
    for (int rt = 0; rt < 4; ++rt)
#pragma unroll
      for (int ct = 0; ct < 4; ++ct)
        acc[rt][ct] = __builtin_amdgcn_mfma_f32_16x16x32_bf16(af[rt], bfr[ct], acc[rt][ct], 0, 0, 0);
  }

#pragma unroll
  for (int rt = 0; rt < 4; ++rt) {
#pragma unroll
    for (int ct = 0; ct < 4; ++ct) {
      int col = n0 + wc + ct * 16 + (lane & 15);
#pragma unroll
      for (int reg = 0; reg < 4; ++reg) {
        int row = m0 + wr + rt * 16 + ((lane >> 4) << 2) + reg;
        if (row < M) {
          float v = acc[rt][ct][reg];
          if (STORE == 2) {
            part[((size_t)z * M + row) * cld + col] = v;
          } else {
            C[(size_t)row * cld + col] = v + ldE(bias, col, md);
          }
        }
      }
    }
  }
}

// reduce partials
template <int ACT, int ADDIN, int BIAS>
__global__ __launch_bounds__(256) void reduce_u(
    const float* __restrict__ part, int KS, int M, int ncols,
    const void* __restrict__ bias0, const void* __restrict__ bias1, long biasoff,
    float* __restrict__ C0, float* __restrict__ C1, int cld, const int* __restrict__ mode) {
  const int md = *mode;
  const int pair = blockIdx.z;
  const void* bias = pair ? bias1 : bias0;
  float* C = pair ? C1 : C0;
  size_t total = (size_t)M * ncols;
  for (size_t i = (size_t)blockIdx.x * blockDim.x + threadIdx.x; i < total;
       i += (size_t)gridDim.x * blockDim.x) {
    int row = (int)(i / ncols), col = (int)(i - (size_t)row * ncols);
    float s = ADDIN ? C[(size_t)row * cld + col] : 0.f;
    for (int ks = 0; ks < KS; ++ks)
      s += part[(((size_t)(pair * KS + ks)) * M + row) * ncols + col];
    if (BIAS) s += ldE(bias, biasoff + col, md);
    if (ACT == 1) s = fmaxf(s, 0.f);
    C[(size_t)row * cld + col] = s;
  }
}

// ============ patch-embed partial GEMM — narrow-path fallback ============
__global__ __launch_bounds__(256) void patch_part(
    const void* __restrict__ x, const void* __restrict__ w,
    float* __restrict__ part, int CPB, const int* __restrict__ mode) {
  const int md = *mode;
  __shared__ float As[25][68];
  __shared__ float Bs[25][68];
  const int m0 = blockIdx.y * 64, n0 = blockIdx.x * 64;
  const int tid = threadIdx.x;
  const int tr = tid >> 4, tc = tid & 15;
  const int z = blockIdx.z;
  float acc[4][4] = {};
  const int c0 = z * CPB;
  for (int c = c0; c < c0 + CPB; ++c) {
    __syncthreads();
    for (int e = tid; e < 1600; e += 256) {
      int p = e / 25, q = e - p * 25;
      int ki = q / 5, li = q - ki * 5;
      int n = m0 + p;
      float v = 0.f;
      if (n < NN) {
        int ni = n / NHP, nj = n - ni * NHP;
        v = ldE(x, (long)c * (HIMG * WIMG) + (5 * ni + ki) * WIMG + 5 * nj + li, md);
      }
      As[q][p] = v;
    }
    for (int e = tid; e < 1600; e += 256) {
      int o = e / 25, q = e - o * 25;
      Bs[q][o] = ldE(w, (long)(n0 + o) * 6400 + c * 25 + q, md);
    }
    __syncthreads();
#pragma unroll
    for (int kk = 0; kk < 25; ++kk) {
      float4 av = *(const float4*)&As[kk][tr * 4];
      float4 bv = *(const float4*)&Bs[kk][tc * 4];
      float a[4] = {av.x, av.y, av.z, av.w};
      float b[4] = {bv.x, bv.y, bv.z, bv.w};
#pragma unroll
      for (int i = 0; i < 4; ++i)
#pragma unroll
        for (int j = 0; j < 4; ++j) acc[i][j] = fmaf(a[i], b[j], acc[i][j]);
    }
  }
#pragma unroll
  for (int i = 0; i < 4; ++i) {
    int row = m0 + tr * 4 + i;
    if (row < NN) {
#pragma unroll
      for (int j = 0; j < 4; ++j)
        part[((size_t)z * NN + row) * 256 + n0 + tc * 4 + j] = acc[i][j];
    }
  }
}

// ============ adj: 128x64 tiled f32 GEMM + per-tile exact top-7 (LDS overlay) ============
__global__ __launch_bounds__(256) void adj_gemm(
    const float* __restrict__ emb, float* __restrict__ pv, unsigned char* __restrict__ pi) {
  __shared__ __align__(16) char pool[43520];
  float (*As)[136] = (float(*)[136])pool;                           // [16][136]
  float (*Bs)[68]  = (float(*)[68])(pool + 8704);                   // [16][68]
  float (*mv)[68]  = (float(*)[68])pool;                            // [128][68] overlay
  unsigned char (*mi)[68] = (unsigned char(*)[68])(pool + 34816);   // [128][68]
  const int m0 = blockIdx.y * 128, n0 = blockIdx.x * 64;
  const int ct = blockIdx.x;
  const int tid = threadIdx.x;
  const int tr = tid >> 4, tc = tid & 15;
  const int ar = tid >> 1, akq = tid & 1;
  const int bn = tid >> 2, bkq = tid & 3;
  const int arow = m0 + ar;
  const int bcol = n0 + bn;
  float acc[8][4] = {};

  float4 pa0 = make_float4(0.f, 0.f, 0.f, 0.f), pa1 = pa0, fb = pa0;
  if (arow < NN) {
    const float* ap = emb + (size_t)arow * 256 + akq * 8;
    pa0 = *(const float4*)ap;
    pa1 = *(const float4*)(ap + 4);
  }
  if (bcol < NN) fb = *(const float4*)(emb + (size_t)bcol * 256 + bkq * 4);

  for (int k0 = 0; k0 < 256; k0 += 16) {
    __syncthreads();
    As[akq * 8 + 0][ar] = pa0.x;
    As[akq * 8 + 1][ar] = pa0.y;
    As[akq * 8 + 2][ar] = pa0.z;
    As[akq * 8 + 3][ar] = pa0.w;
    As[akq * 8 + 4][ar] = pa1.x;
    As[akq * 8 + 5][ar] = pa1.y;
    As[akq * 8 + 6][ar] = pa1.z;
    As[akq * 8 + 7][ar] = pa1.w;
    Bs[bkq * 4 + 0][bn] = fb.x;
    Bs[bkq * 4 + 1][bn] = fb.y;
    Bs[bkq * 4 + 2][bn] = fb.z;
    Bs[bkq * 4 + 3][bn] = fb.w;
    __syncthreads();
    if (k0 + 16 < 256) {
      if (arow < NN) {
        const float* ap = emb + (size_t)arow * 256 + k0 + 16 + akq * 8;
        pa0 = *(const float4*)ap;
        pa1 = *(const float4*)(ap + 4);
      }
      if (bcol < NN) fb = *(const float4*)(emb + (size_t)bcol * 256 + k0 + 16 + bkq * 4);
    }
#pragma unroll
    for (int kk = 0; kk < 16; ++kk) {
      float4 a0 = *(const float4*)&As[kk][tr * 8];
      float4 a1 = *(const float4*)&As[kk][tr * 8 + 4];
      float4 bv = *(const float4*)&Bs[kk][tc * 4];
      float a[8] = {a0.x, a0.y, a0.z, a0.w, a1.x, a1.y, a1.z, a1.w};
      float b[4] = {bv.x, bv.y, bv.z, bv.w};
#pragma unroll
      for (int i = 0; i < 8; ++i)
#pragma unroll
        for (int j = 0; j < 4; ++j) acc[i][j] = fmaf(a[i], b[j], acc[i][j]);
    }
  }
  __syncthreads();   // staging dead; safe to overlay mv/mi

  // per-thread sort of 4 cols per row (8 rows), (val desc, idx asc)
#pragma unroll
  for (int i = 0; i < 8; ++i) {
    float v[4]; int id[4];
#pragma unroll
    for (int j = 0; j < 4; ++j) {
      int cl = tc * 4 + j;
      int valid = (n0 + cl) < NN;
      v[j] = valid ? acc[i][j] : -1e38f;
      id[j] = valid ? cl : 255;
    }
#pragma unroll
    for (int a = 1; a < 4; ++a) {
      float va = v[a]; int ia = id[a];
      int b = a;
      while (b > 0 && (va > v[b - 1] || (va == v[b - 1] && ia < id[b - 1]))) {
        v[b] = v[b - 1]; id[b] = id[b - 1]; --b;
      }
      v[b] = va; id[b] = ia;
    }
    int rl = tr * 8 + i;
#pragma unroll
    for (int s = 0; s < 4; ++s) {
      mv[rl][tc * 4 + s] = v[s];
      mi[rl][tc * 4 + s] = (unsigned char)id[s];
    }
  }
  __syncthreads();

  // one thread per row (128): merge 16 sorted 4-lists -> sorted top-7 for this col tile
  if (tid < 128) {
    int row = m0 + tid;
    if (row < NN) {
      int ptr[16];
#pragma unroll
      for (int g = 0; g < 16; ++g) ptr[g] = 0;
      for (int k = 0; k < 7; ++k) {
        float best = -1e38f; int bid = 0x7fffffff; int bg = 0;
        for (int g = 0; g < 16; ++g) {
          if (ptr[g] < 4) {
            float vv = mv[tid][g * 4 + ptr[g]];
            int ii = mi[tid][g * 4 + ptr[g]];
            if (vv > best || (vv == best && ii < bid)) { best = vv; bid = ii; bg = g; }
          }
        }
        ptr[bg]++;
        pv[(size_t)row * (NCT * 7) + ct * 7 + k] = best;
        pi[(size_t)row * (NCT * 7) + ct * 7 + k] = (unsigned char)bid;
      }
    }
  }
}

// wave-parallel merge: one wave per row, lane c = list c head; 7x butterfly argmax (exact)
__global__ __launch_bounds__(256) void adj_merge57(
    const float* __restrict__ pv, const unsigned char* __restrict__ pi,
    int* __restrict__ idx_o, int* __restrict__ keep_o) {
  const int wid = threadIdx.x >> 6, lane = threadIdx.x & 63;
  const int row = blockIdx.x * 4 + wid;
  if (row >= NN) return;
  const size_t base = (size_t)row * (NCT * 7);
  int p = 0;
  float mval = -1e38f;
  int mid = 0x7fffffff;
  if (lane < NCT) {
    mval = pv[base + lane * 7];
    mid = lane * 64 + (int)pi[base + lane * 7];
  }
  for (int k = 0; k < 7; ++k) {
    float v = mval; int i = mid;
#pragma unroll
    for (int off = 32; off > 0; off >>= 1) {
      float ov = __shfl_xor(v, off, 64);
      int oi = __shfl_xor(i, off, 64);
      if (ov > v || (ov == v && oi < i)) { v = ov; i = oi; }
    }
    if (lane == 0) {
      idx_o[row * 7 + k] = i;
      keep_o[row * 7 + k] = (i > row && v != 0.0f) ? 1 : 0;
    }
    if (mval == v && mid == i) {
      ++p;
      if (p < 7) {
        mval = pv[base + lane * 7 + p];
        mid = lane * 64 + (int)pi[base + lane * 7 + p];
      } else {
        mval = -1e38f; mid = 0x7fffffff;
      }
    }
  }
}

// ---------------- spatial kNN via 5x5 window ----------------
__global__ __launch_bounds__(256) void spatial_topk(int* __restrict__ idx_o, int* __restrict__ keep_o) {
  int r = blockIdx.x * 256 + threadIdx.x;
  if (r >= NN) return;
  int ri = r / NHP, rj = r - (r / NHP) * NHP;
  int bd[7], bi[7];
#pragma unroll
  for (int k = 0; k < 7; ++k) { bd[k] = 0x7fffffff; bi[k] = 0x7fffffff; }
  int ilo = ri - 2 > 0 ? ri - 2 : 0, ihi = ri + 2 < NHP - 1 ? ri + 2 : NHP - 1;
  int jlo = rj - 2 > 0 ? rj - 2 : 0, jhi = rj + 2 < NHP - 1 ? rj + 2 : NHP - 1;
  for (int i2 = ilo; i2 <= ihi; ++i2) {
    int dy = ri - i2; int dy2 = dy * dy;
    for (int j2 = jlo; j2 <= jhi; ++j2) {
      int dx = rj - j2;
      int d = dy2 + dx * dx;
      int m = i2 * NHP + j2;
      if (d < bd[6]) {
        int pq = 6;
        while (pq > 0 && d < bd[pq - 1]) { bd[pq] = bd[pq - 1]; bi[pq] = bi[pq - 1]; --pq; }
        bd[pq] = d; bi[pq] = m;
      }
    }
  }
#pragma unroll
  for (int k = 0; k < 7; ++k) {
    idx_o[r * 7 + k] = bi[k];
    keep_o[r * 7 + k] = (bi[k] >= r && bd[k] != 0) ? 1 : 0;
  }
}

// ---------------- GATv2 aggregation, single head (stride 256, f32 out) ----------------
__global__ __launch_bounds__(256) void gat_agg1(
    const float* __restrict__ xl, const float* __restrict__ xr,
    const void* __restrict__ att, long attoff, const void* __restrict__ gbias, long gboff,
    const int* __restrict__ nbr, const int* __restrict__ keep,
    float* __restrict__ out, const int* __restrict__ mode) {
  const int md = *mode;
  const int r = blockIdx.x;
  const int f = threadIdx.x;
  __shared__ int s_src[8];
  __shared__ int s_mask_s;
  __shared__ float red[4][8];
  if (f < 7) {
    int v = nbr[r * 7 + f];
    s_src[f] = ((unsigned)v < (unsigned)NN) ? v : 0;
  }
  if (f == 7) s_src[7] = r;
  if (f == 0) {
    int mk = 0x80;
    for (int e = 0; e < 7; ++e)
      if (keep[r * 7 + e] != 0) mk |= (1 << e);
    s_mask_s = mk;
  }
  __syncthreads();
  const int mask = s_mask_s;
  const int wid = f >> 6, lane = f & 63;

  float xrv = xr[(size_t)r * 256 + f];
  float attv = ldE(att, attoff + f, md);
  float xlv[8], part[8];
#pragma unroll
  for (int e = 0; e < 8; ++e) {
    xlv[e] = 0.f; part[e] = 0.f;
    if (mask & (1 << e)) {
      float v = xl[(size_t)s_src[e] * 256 + f];
      xlv[e] = v;
      float s = v + xrv;
      s = s > 0.f ? s : 0.2f * s;
      part[e] = s * attv;
    }
  }
#pragma unroll
  for (int e = 0; e < 8; ++e) {
    float v = part[e];
#pragma unroll
    for (int off = 32; off > 0; off >>= 1) v += __shfl_xor(v, off, 64);
    if (lane == 0) red[wid][e] = v;
  }
  __syncthreads();
  float m = -1e38f;
  float logit[8];
#pragma unroll
  for (int e = 0; e < 8; ++e) {
    logit[e] = red[0][e] + red[1][e] + red[2][e] + red[3][e];
    if (mask & (1 << e)) m = fmaxf(m, logit[e]);
  }
  float den = 0.f, al[8];
#pragma unroll
  for (int e = 0; e < 8; ++e) {
    al[e] = (mask & (1 << e)) ? expf(logit[e] - m) : 0.f;
    den += al[e];
  }
  float inv = 1.0f / den;
  float o = 0.f;
#pragma unroll
  for (int e = 0; e < 8; ++e) o = fmaf(al[e], xlv[e], o);
  o = o * inv + ldE(gbias, gboff + f, md);
  o = o > 0.f ? o : expm1f(o);
  out[(size_t)r * 256 + f] = o;
}

// ------- GATv2 aggregation, per-(node, head) grid (stride 2048), bf16 output -------
__global__ __launch_bounds__(256) void gat_agg8h(
    const float* __restrict__ xl, const float* __restrict__ xr,
    const void* __restrict__ att, const void* __restrict__ gbias,
    const int* __restrict__ nbr, const int* __restrict__ keep,
    unsigned short* __restrict__ out, const int* __restrict__ mode) {
  const int md = *mode;
  const int r = blockIdx.x;
  const int h = blockIdx.y;
  const int f = threadIdx.x;
  __shared__ int s_src[8];
  __shared__ int s_mask_s;
  __shared__ float red[4][8];
  if (f < 7) {
    int v = nbr[r * 7 + f];
    s_src[f] = ((unsigned)v < (unsigned)NN) ? v : 0;
  }
  if (f == 7) s_src[7] = r;
  if (f == 0) {
    int mk = 0x80;
    for (int e = 0; e < 7; ++e)
      if (keep[r * 7 + e] != 0) mk |= (1 << e);
    s_mask_s = mk;
  }
  __syncthreads();
  const int mask = s_mask_s;
  const int wid = f >> 6, lane = f & 63;

  float xrv = xr[(size_t)r * 2048 + h * 256 + f];
  float attv = ldE(att, h * 256 + f, md);
  float xlv[8], part[8];
#pragma unroll
  for (int e = 0; e < 8; ++e) {
    xlv[e] = 0.f; part[e] = 0.f;
    if (mask & (1 << e)) {
      float v = xl[(size_t)s_src[e] * 2048 + h * 256 + f];
      xlv[e] = v;
      float s = v + xrv;
      s = s > 0.f ? s : 0.2f * s;
      part[e] = s * attv;
    }
  }
#pragma unroll
  for (int e = 0; e < 8; ++e) {
    float v = part[e];
#pragma unroll
    for (int off = 32; off > 0; off >>= 1) v += __shfl_xor(v, off, 64);
    if (lane == 0) red[wid][e] = v;
  }
  __syncthreads();
  float m = -1e38f;
  float logit[8];
#pragma unroll
  for (int e = 0; e < 8; ++e) {
    logit[e] = red[0][e] + red[1][e] + red[2][e] + red[3][e];
    if (mask & (1 << e)) m = fmaxf(m, logit[e]);
  }
  float den = 0.f, al[8];
#pragma unroll
  for (int e = 0; e < 8; ++e) {
    al[e] = (mask & (1 << e)) ? expf(logit[e] - m) : 0.f;
    den += al[e];
  }
  float inv = 1.0f / den;
  float o = 0.f;
#pragma unroll
  for (int e = 0; e < 8; ++e) o = fmaf(al[e], xlv[e], o);
  o = o * inv + ldE(gbias, h * 256 + f, md);
  o = o > 0.f ? o : expm1f(o);
  out[(size_t)r * 2048 + h * 256 + f] = f2bf(o);   // same rounding as cvt_bf16 did
}

// ---------------- final: out = relu(cat(h2,h4)@fc3 + b) + h4 ----------------
__global__ __launch_bounds__(256) void fc3_final(
    const float* __restrict__ h2, const float* __restrict__ h4,
    const void* __restrict__ B, const void* __restrict__ bias,
    void* __restrict__ outp, const int* __restrict__ mode) {
  const int md = *mode;
  __shared__ float As[16][68];
  __shared__ float Bs[16][68];
  const int m0 = blockIdx.y * 64, n0 = blockIdx.x * 64;
  const int tid = threadIdx.x;
  const int tr = tid >> 4, tc = tid & 15;
  const int ar = tid >> 2, akq = tid & 3;
  const int bkr = tid >> 4, bnc = tid & 15;
  const int arow = m0 + ar;
  float acc[4][4] = {};

  for (int k0 = 0; k0 < 512; k0 += 16) {
    __syncthreads();
    {
      int k = k0 + akq * 4;
      float4 v = make_float4(0.f, 0.f, 0.f, 0.f);
      if (arow < NN) {
        const float* src = (k < 256) ? (h2 + (size_t)arow * 256 + k)
                                     : (h4 + (size_t)arow * 256 + (k - 256));
        v = *(const float4*)src;
      }
      As[akq * 4 + 0][ar] = v.x;
      As[akq * 4 + 1][ar] = v.y;
      As[akq * 4 + 2][ar] = v.z;
      As[akq * 4 + 3][ar] = v.w;
    }
    {
      long bidx = (long)(k0 + bkr) * 256 + n0 + bnc * 4;
      if (md) {
        ushort4 u = *(const ushort4*)((const unsigned short*)B + bidx);
        Bs[bkr][bnc * 4 + 0] = bf2f(u.x);
        Bs[bkr][bnc * 4 + 1] = bf2f(u.y);
        Bs[bkr][bnc * 4 + 2] = bf2f(u.z);
        Bs[bkr][bnc * 4 + 3] = bf2f(u.w);
      } else {
        float4 v = *(const float4*)((const float*)B + bidx);
        Bs[bkr][bnc * 4 + 0] = v.x;
        Bs[bkr][bnc * 4 + 1] = v.y;
        Bs[bkr][bnc * 4 + 2] = v.z;
        Bs[bkr][bnc * 4 + 3] = v.w;
      }
    }
    __syncthreads();
#pragma unroll
    for (int kk = 0; kk < 16; ++kk) {
      float4 av = *(const float4*)&As[kk][tr * 4];
      float4 bv = *(const float4*)&Bs[kk][tc * 4];
      float a[4] = {av.x, av.y, av.z, av.w};
      float b[4] = {bv.x, bv.y, bv.z, bv.w};
#pragma unroll
      for (int i = 0; i < 4; ++i)
#pragma unroll
        for (int j = 0; j < 4; ++j) acc[i][j] = fmaf(a[i], b[j], acc[i][j]);
    }
  }
#pragma unroll
  for (int i = 0; i < 4; ++i) {
    int row = m0 + tr * 4 + i;
    if (row < NN) {
#pragma unroll
      for (int j = 0; j < 4; ++j) {
        int col = n0 + tc * 4 + j;
        float v = fmaxf(acc[i][j] + ldE(bias, col, md), 0.f) + h4[(size_t)row * 256 + col];
        if (md) ((__hip_bfloat16*)outp)[(size_t)row * 256 + col] = __float2bfloat16(v);
        else ((float*)outp)[(size_t)row * 256 + col] = v;
      }
    }
  }
}

// ---------------- launcher ----------------
extern "C" void kernel_launch(void* const* d_in, const int* in_sizes, int n_in,
                              void* d_out, int out_size, void* d_ws, size_t ws_size,
                              hipStream_t stream) {
  (void)in_sizes; (void)n_in; (void)out_size;
  const void* x    = d_in[0];
  const void* w1   = d_in[1];
  const void* b1   = d_in[2];
  const void* fc2w = d_in[3];
  const void* fc2b = d_in[4];
  const void* fc3w = d_in[5];
  const void* fc3b = d_in[6];
  const void* g_wl[4]   = {d_in[7],  d_in[13], d_in[19], d_in[25]};
  const void* g_bl[4]   = {d_in[8],  d_in[14], d_in[20], d_in[26]};
  const void* g_wr[4]   = {d_in[9],  d_in[15], d_in[21], d_in[27]};
  const void* g_br[4]   = {d_in[10], d_in[16], d_in[22], d_in[28]};
  const void* g_att[4]  = {d_in[11], d_in[17], d_in[23], d_in[29]};
  const void* g_bias[4] = {d_in[12], d_in[18], d_in[24], d_in[30]};

  float* ws = (float*)d_ws;
  int* mode = (int*)d_ws;
  size_t off = 64;
  float* emb = ws + off; off += (size_t)NN * 256;
  float* xl2 = ws + off; off += (size_t)NN * 256;
  float* xr2 = ws + off; off += (size_t)NN * 256;
  float* h2  = ws + off; off += (size_t)NN * 256;
  float* h4  = ws + off; off += (size_t)NN * 256;
  int* idx1  = (int*)(ws + off); off += NN * 7;
  int* keep1 = (int*)(ws + off); off += NN * 7;
  int* idx2  = (int*)(ws + off); off += NN * 7;
  int* keep2 = (int*)(ws + off); off += NN * 7;
  unsigned short* emb_bf = (unsigned short*)(ws + off); off += (size_t)NN * 256 / 2;
  unsigned short* wbfL   = (unsigned short*)(ws + off); off += (size_t)524288 / 2;
  unsigned short* wbfR   = (unsigned short*)(ws + off); off += (size_t)524288 / 2;
  float* scratch = ws + off;
  const size_t wide_need = off + 3 * (size_t)NN * 2048;          // ~111.3 MB
  const bool wide = ws_size >= wide_need * sizeof(float);

  float* emb1 = h2;            // conv output; dead before h2 is written
  float* pv = scratch;         // adj scratch (after conv partials die)
  unsigned char* pi = (unsigned char*)(scratch + (size_t)NN * (NCT * 7));

  dim3 blk(256);
  const int* idxs[2]  = {idx1, idx2};
  const int* keeps[2] = {keep1, keep2};
  float* houts[2] = {h2, h4};
  const int* f32mode = mode + 1;

  detect_mode<<<dim3(1), blk, 0, stream>>>((const unsigned short*)x, mode);

  if (wide) {
    // conv via im2col halves + K-split f32 GEMM (pipelined 128x64, 8 chunks/half)
    float* wT   = scratch;
    float* part = wT + (size_t)6400 * 256;
    float* a2   = part + 8 * (size_t)NN * 256;

    wtrans<<<dim3(200, 8), blk, 0, stream>>>(w1, wT, mode);
    for (int h = 0; h < 2; ++h) {
      im2col<<<dim3(2048), blk, 0, stream>>>(x, a2, h, mode);
      gemm_f84<<<dim3(4, 29, 8), blk, 0, stream>>>(a2, wT, (long)h * 3200 * 256,
                                                   part, NN, 3200, 400, 256);
      if (h == 0)
        reduce_u<0, 0, 0><<<dim3(1024, 1, 1), blk, 0, stream>>>(part, 8, NN, 256,
                                                                b1, b1, 0, emb1, emb1, 256, mode);
      else
        reduce_u<1, 1, 1><<<dim3(1024, 1, 1), blk, 0, stream>>>(part, 8, NN, 256,
                                                                b1, b1, 0, emb1, emb1, 256, mode);
    }
  } else {
    const int convKS = 2;
    patch_part<<<dim3(4, 57, convKS), blk, 0, stream>>>(x, w1, scratch, 256 / convKS, mode);
    reduce_u<1, 0, 1><<<dim3(1024, 1, 1), blk, 0, stream>>>(scratch, convKS, NN, 256,
                                                            b1, b1, 0, emb1, emb1, 256, mode);
  }

  // fc2 -> emb (f32)
  gemm_u<0, 1><<<dim3(4, 57, 1), blk, 0, stream>>>(emb1, fc2w, fc2w, 0, fc2b, fc2b, 0,
                                                   emb, emb, nullptr, 256,
                                                   NN, 256, 256, 1, 256, mode);
  // graphs (f32, exact)
  adj_gemm<<<dim3(NCT, 29), blk, 0, stream>>>(emb, pv, pi);
  adj_merge57<<<dim3(900), blk, 0, stream>>>(pv, pi, idx1, keep1);
  spatial_topk<<<dim3(15), blk, 0, stream>>>(idx2, keep2);

  if (wide) {
    float* xl_w = scratch;
    float* xr_w = xl_w + (size_t)NN * 2048;
    float* hh_w = xr_w + (size_t)NN * 2048;
    unsigned short* hh_bf = (unsigned short*)hh_w;   // gat_agg8h writes bf16 here directly
    float* g24part = xr_w;                           // aliases xr_w (dead after gat_agg8h)

    cvt_bf16<<<dim3(512), blk, 0, stream>>>(emb, emb_bf, (long)NN * 64);

    for (int g = 0; g < 2; ++g) {
      int a = g * 2, b = g * 2 + 1;
      wconvT2<<<dim3(8, 64, 2), blk, 0, stream>>>(g_wl[a], g_wr[a], wbfL, wbfR, 256, 2048, mode);
      gemm_mf<0><<<dim3(16, 29, 2), blk, 0, stream>>>(emb_bf, wbfL, wbfR,
                                                      g_bl[a], g_br[a],
                                                      xl_w, xr_w, nullptr, 2048,
                                                      NN, 256, 256, 1, mode);
      gat_agg8h<<<dim3(NN, 8), blk, 0, stream>>>(xl_w, xr_w, g_att[a], g_bias[a],
                                                 idxs[g], keeps[g], hh_bf, mode);
      wconvT2<<<dim3(64, 8, 2), blk, 0, stream>>>(g_wl[b], g_wr[b], wbfL, wbfR, 2048, 256, mode);
      gemm_mf<2><<<dim3(2, 29, 8), blk, 0, stream>>>(hh_bf, wbfL, wbfR,
                                                     nullptr, nullptr,
                                                     nullptr, nullptr, g24part, 256,
                                                     NN, 2048, 512, 4, mode);
      reduce_u<0, 0, 1><<<dim3(1024, 1, 2), blk, 0, stream>>>(g24part, 4, NN, 256,
                                                              g_bl[b], g_br[b], 0,
                                                              xl2, xr2, 256, mode);
      gat_agg1<<<dim3(NN), blk, 0, stream>>>(xl2, xr2, g_att[b], 0, g_bias[b], 0,
                                             idxs[g], keeps[g], houts[g], mode);
    }
  } else {
    float* xlh = scratch;
    float* xrh = xlh + (size_t)NN * 256;
    float* hh  = xrh + (size_t)NN * 256;

    for (int g = 0; g < 2; ++g) {
      int a = g * 2, b = g * 2 + 1;
      for (int h = 0; h < 8; ++h) {
        gemm_u<0, 0><<<dim3(4, 57, 2), blk, 0, stream>>>(emb, g_wl[a], g_wr[a], h * 256,
                                                         g_bl[a], g_br[a], h * 256,
                                                         xlh, xrh, nullptr, 256,
                                                         NN, 256, 256, 1, 2048, mode);
        gat_agg1<<<dim3(NN), blk, 0, stream>>>(xlh, xrh, g_att[a], h * 256, g_bias[a], h * 256,
                                               idxs[g], keeps[g], hh, mode);
        if (h == 0) {
          gemm_u<0, 0><<<dim3(4, 57, 2), blk, 0, stream>>>(hh, g_wl[b], g_wr[b], 0,
                                                           g_bl[b], g_br[b], 0,
                                                           xl2, xr2, nullptr, 256,
                                                           NN, 256, 256, 1, 256, mode);
        } else {
          gemm_u<1, 0><<<dim3(4, 57, 2), blk, 0, stream>>>(hh, g_wl[b], g_wr[b], (long)h * 256 * 256,
                                                           g_bl[b], g_br[b], 0,
                                                           xl2, xr2, nullptr, 256,
                                                           NN, 256, 256, 1, 256, mode);
        }
      }
      gat_agg1<<<dim3(NN), blk, 0, stream>>>(xl2, xr2, g_att[b], 0, g_bias[b], 0,
                                             idxs[g], keeps[g], houts[g], mode);
    }
  }

  fc3_final<<<dim3(4, 57), blk, 0, stream>>>(h2, h4, fc3w, fc3b, d_out, mode);
}

// Round 14
// 912.817 us; speedup vs baseline: 1.0219x; 1.0219x over previous
//
#include <hip/hip_runtime.h>
#include <hip/hip_bf16.h>
#include <math.h>

#define NN 3600
#define HIMG 300
#define WIMG 300
#define NHP 60
#define NCT 57   // ceil(3600/64) column tiles for adj

typedef __attribute__((ext_vector_type(8))) short bf16x8;
typedef __attribute__((ext_vector_type(4))) float f32x4;

__device__ __forceinline__ float bf2f(unsigned short u) {
  union { unsigned int i; float f; } v; v.i = ((unsigned int)u) << 16; return v.f;
}
__device__ __forceinline__ float ldE(const void* p, long i, int md) {
  return md ? bf2f(((const unsigned short*)p)[i]) : ((const float*)p)[i];
}
__device__ __forceinline__ unsigned short f2bf(float f) {
  __hip_bfloat16 h = __float2bfloat16(f);
  return *(unsigned short*)&h;
}

// flag[0] = detected mode, flag[1] = 0 (f32-mode const for ws buffers)
__global__ __launch_bounds__(256) void detect_mode(
    const unsigned short* __restrict__ x, int* __restrict__ flag) {
  __shared__ int bad;
  if (threadIdx.x == 0) bad = 0;
  __syncthreads();
  int b = 0;
  for (int i = threadIdx.x; i < 8192; i += 256) {
    int e = (x[i] >> 7) & 0xFF;
    if (e >= 0x90) b = 1;
  }
  if (b) atomicOr(&bad, 1);
  __syncthreads();
  if (threadIdx.x == 0) {
    flag[0] = bad ? 0 : 1;
    flag[1] = 0;
  }
}

// ---------------- w[o][k] -> wT[k][o] (f32) ----------------
__global__ __launch_bounds__(256) void wtrans(
    const void* __restrict__ w, float* __restrict__ wT, const int* __restrict__ mode) {
  const int md = *mode;
  __shared__ float t[32][33];
  const int k0 = blockIdx.x * 32, o0 = blockIdx.y * 32;
  const int tx = threadIdx.x & 31, ty = threadIdx.x >> 5;
#pragma unroll
  for (int s = 0; s < 32; s += 8)
    t[ty + s][tx] = ldE(w, (long)(o0 + ty + s) * 6400 + k0 + tx, md);
  __syncthreads();
#pragma unroll
  for (int s = 0; s < 32; s += 8)
    wT[(size_t)(k0 + ty + s) * 256 + o0 + tx] = t[tx][ty + s];
}

// -------- weight convert+transpose bf16, L/R fused via z: src [K][N] -> dst [N][K] --------
__global__ __launch_bounds__(256) void wconvT2(
    const void* __restrict__ srcL, const void* __restrict__ srcR,
    unsigned short* __restrict__ dstL, unsigned short* __restrict__ dstR,
    int Kd, int Nd, const int* __restrict__ mode) {
  const int md = *mode;
  const void* src = blockIdx.z ? srcR : srcL;
  unsigned short* dst = blockIdx.z ? dstR : dstL;
  __shared__ float t[32][33];
  const int k0 = blockIdx.x * 32, n0 = blockIdx.y * 32;
  const int tx = threadIdx.x & 31, ty = threadIdx.x >> 5;
#pragma unroll
  for (int s = 0; s < 32; s += 8)
    t[ty + s][tx] = ldE(src, (long)(k0 + ty + s) * Nd + n0 + tx, md);
  __syncthreads();
#pragma unroll
  for (int s = 0; s < 32; s += 8)
    dst[(size_t)(n0 + ty + s) * Kd + k0 + tx] = f2bf(t[tx][ty + s]);
}

// -------- flat f32 -> bf16 --------
__global__ __launch_bounds__(256) void cvt_bf16(
    const float* __restrict__ src, unsigned short* __restrict__ dst, long n4) {
  for (long i = (long)blockIdx.x * 256 + threadIdx.x; i < n4; i += (long)gridDim.x * 256) {
    float4 v = *(const float4*)(src + i * 4);
    ushort4 o;
    o.x = f2bf(v.x); o.y = f2bf(v.y); o.z = f2bf(v.z); o.w = f2bf(v.w);
    *(ushort4*)(dst + i * 4) = o;
  }
}

// ---------------- im2col (one K-half) ----------------
__global__ __launch_bounds__(256) void im2col(
    const void* __restrict__ x, float* __restrict__ a2, int h, const int* __restrict__ mode) {
  const int md = *mode;
  const int total = NN * 3200;
  for (int i = blockIdx.x * 256 + threadIdx.x; i < total; i += gridDim.x * 256) {
    int n = i / 3200, kl = i - n * 3200;
    int k = h * 3200 + kl;
    int c = k / 25, q = k - c * 25;
    int ki = q / 5, li = q - ki * 5;
    int ni = n / NHP, nj = n - ni * NHP;
    a2[i] = ldE(x, (long)c * (HIMG * WIMG) + (5 * ni + ki) * WIMG + 5 * nj + li, md);
  }
}

// ======== 128x64 f32 partial GEMM, 8x4/thread, reg-prefetch pipelined (conv) ========
__global__ __launch_bounds__(256) void gemm_f84(
    const float* __restrict__ A, const float* __restrict__ B, long boff,
    float* __restrict__ part, int M, int lda, int kchunk, int ldb) {
  __shared__ float As[16][136];
  __shared__ float Bs[16][68];
  const int m0 = blockIdx.y * 128, n0 = blockIdx.x * 64;
  const int z = blockIdx.z;
  const int tid = threadIdx.x;
  const int tr = tid >> 4, tc = tid & 15;
  const int ar = tid >> 1, akq = tid & 1;
  const int bkr = tid >> 4, bnc = tid & 15;
  const int arow = m0 + ar;
  float acc[8][4] = {};

  const int kb = z * kchunk, ke = kb + kchunk;
  float4 pa0 = make_float4(0.f, 0.f, 0.f, 0.f), pa1 = pa0, pb;
  if (arow < M) {
    const float* ap = A + (size_t)arow * lda + kb + akq * 8;
    pa0 = *(const float4*)ap;
    pa1 = *(const float4*)(ap + 4);
  }
  pb = *(const float4*)(B + (size_t)(kb + bkr) * ldb + boff + n0 + bnc * 4);

  for (int k0 = kb; k0 < ke; k0 += 16) {
    __syncthreads();
    As[akq * 8 + 0][ar] = pa0.x;
    As[akq * 8 + 1][ar] = pa0.y;
    As[akq * 8 + 2][ar] = pa0.z;
    As[akq * 8 + 3][ar] = pa0.w;
    As[akq * 8 + 4][ar] = pa1.x;
    As[akq * 8 + 5][ar] = pa1.y;
    As[akq * 8 + 6][ar] = pa1.z;
    As[akq * 8 + 7][ar] = pa1.w;
    Bs[bkr][bnc * 4 + 0] = pb.x;
    Bs[bkr][bnc * 4 + 1] = pb.y;
    Bs[bkr][bnc * 4 + 2] = pb.z;
    Bs[bkr][bnc * 4 + 3] = pb.w;
    __syncthreads();
    if (k0 + 16 < ke) {
      if (arow < M) {
        const float* ap = A + (size_t)arow * lda + (k0 + 16) + akq * 8;
        pa0 = *(const float4*)ap;
        pa1 = *(const float4*)(ap + 4);
      }
      pb = *(const float4*)(B + (size_t)(k0 + 16 + bkr) * ldb + boff + n0 + bnc * 4);
    }
#pragma unroll
    for (int kk = 0; kk < 16; ++kk) {
      float4 a0 = *(const float4*)&As[kk][tr * 8];
      float4 a1 = *(const float4*)&As[kk][tr * 8 + 4];
      float4 bv = *(const float4*)&Bs[kk][tc * 4];
      float a[8] = {a0.x, a0.y, a0.z, a0.w, a1.x, a1.y, a1.z, a1.w};
      float b[4] = {bv.x, bv.y, bv.z, bv.w};
#pragma unroll
      for (int i = 0; i < 8; ++i)
#pragma unroll
        for (int j = 0; j < 4; ++j) acc[i][j] = fmaf(a[i], b[j], acc[i][j]);
    }
  }
#pragma unroll
  for (int i = 0; i < 8; ++i) {
    int row = m0 + tr * 8 + i;
    if (row < M) {
#pragma unroll
      for (int j = 0; j < 4; ++j)
        part[((size_t)z * M + row) * 256 + n0 + tc * 4 + j] = acc[i][j];
    }
  }
}

// ================= unified 64x64 f32 GEMM (fc2 / narrow path) =================
template <int STORE, int ACT>
__global__ __launch_bounds__(256) void gemm_u(
    const float* __restrict__ A, const void* __restrict__ B0, const void* __restrict__ B1,
    long boff, const void* __restrict__ bias0, const void* __restrict__ bias1, long biasoff,
    float* __restrict__ C0, float* __restrict__ C1, float* __restrict__ part, int cld,
    int M, int lda, int kchunk, int KS, int ldb, const int* __restrict__ mode) {
  const int md = *mode;
  const int z = blockIdx.z;
  const int pair = z / KS, ks = z - pair * KS;
  const void* B = pair ? B1 : B0;
  const void* bias = pair ? bias1 : bias0;
  float* C = pair ? C1 : C0;
  __shared__ float As[16][68];
  __shared__ float Bs[16][68];
  const int m0 = blockIdx.y * 64, n0 = blockIdx.x * 64;
  const int tid = threadIdx.x;
  const int tr = tid >> 4, tc = tid & 15;
  const int ar = tid >> 2, akq = tid & 3;
  const int bkr = tid >> 4, bnc = tid & 15;
  const int arow = m0 + ar;
  float acc[4][4] = {};

  const int kb = ks * kchunk, ke = kb + kchunk;
  for (int k0 = kb; k0 < ke; k0 += 16) {
    __syncthreads();
    {
      float4 v = make_float4(0.f, 0.f, 0.f, 0.f);
      if (arow < M) v = *(const float4*)(A + (size_t)arow * lda + k0 + akq * 4);
      As[akq * 4 + 0][ar] = v.x;
      As[akq * 4 + 1][ar] = v.y;
      As[akq * 4 + 2][ar] = v.z;
      As[akq * 4 + 3][ar] = v.w;
    }
    {
      long bidx = (long)(k0 + bkr) * ldb + boff + n0 + bnc * 4;
      if (md) {
        ushort4 u = *(const ushort4*)((const unsigned short*)B + bidx);
        Bs[bkr][bnc * 4 + 0] = bf2f(u.x);
        Bs[bkr][bnc * 4 + 1] = bf2f(u.y);
        Bs[bkr][bnc * 4 + 2] = bf2f(u.z);
        Bs[bkr][bnc * 4 + 3] = bf2f(u.w);
      } else {
        float4 v = *(const float4*)((const float*)B + bidx);
        Bs[bkr][bnc * 4 + 0] = v.x;
        Bs[bkr][bnc * 4 + 1] = v.y;
        Bs[bkr][bnc * 4 + 2] = v.z;
        Bs[bkr][bnc * 4 + 3] = v.w;
      }
    }
    __syncthreads();
#pragma unroll
    for (int kk = 0; kk < 16; ++kk) {
      float4 av = *(const float4*)&As[kk][tr * 4];
      float4 bv = *(const float4*)&Bs[kk][tc * 4];
      float a[4] = {av.x, av.y, av.z, av.w};
      float b[4] = {bv.x, bv.y, bv.z, bv.w};
#pragma unroll
      for (int i = 0; i < 4; ++i)
#pragma unroll
        for (int j = 0; j < 4; ++j) acc[i][j] = fmaf(a[i], b[j], acc[i][j]);
    }
  }
#pragma unroll
  for (int i = 0; i < 4; ++i) {
    int row = m0 + tr * 4 + i;
    if (row < M) {
#pragma unroll
      for (int j = 0; j < 4; ++j) {
        int col = n0 + tc * 4 + j;
        if (STORE == 2) {
          part[((size_t)z * M + row) * cld + col] = acc[i][j];
        } else if (STORE == 1) {
          C[(size_t)row * cld + col] += acc[i][j];
        } else {
          float v = acc[i][j] + ldE(bias, biasoff + col, md);
          if (ACT == 1) v = fmaxf(v, 0.f);
          C[(size_t)row * cld + col] = v;
        }
      }
    }
  }
}

// ================= MFMA bf16 GEMM, reg-prefetch pipelined =================
template <int STORE>
__global__ __launch_bounds__(256) void gemm_mf(
    const unsigned short* __restrict__ A,
    const unsigned short* __restrict__ B0, const unsigned short* __restrict__ B1,
    const void* __restrict__ bias0, const void* __restrict__ bias1,
    float* __restrict__ C0, float* __restrict__ C1, float* __restrict__ part, int cld,
    int M, int K, int kchunk, int KS, const int* __restrict__ mode) {
  const int md = *mode;
  const int z = blockIdx.z;
  const int pair = z / KS, ks = z - pair * KS;
  const unsigned short* B = pair ? B1 : B0;
  const void* bias = pair ? bias1 : bias0;
  float* C = pair ? C1 : C0;

  __shared__ __align__(16) unsigned short Al[128][40];
  __shared__ __align__(16) unsigned short Bl[128][40];
  const int m0 = blockIdx.y * 128, n0 = blockIdx.x * 128;
  const int tid = threadIdx.x;
  const int lane = tid & 63, w = tid >> 6;
  const int wr = (w >> 1) * 64, wc = (w & 1) * 64;
  const int frow = lane & 15, fk = (lane >> 4) * 8;
  const int sr0 = tid >> 2, skc0 = (tid & 3) << 3;
  const int sr1 = (tid + 256) >> 2, skc1 = ((tid + 256) & 3) << 3;

  f32x4 acc[4][4];
#pragma unroll
  for (int i = 0; i < 4; ++i)
#pragma unroll
    for (int j = 0; j < 4; ++j) acc[i][j] = (f32x4){0.f, 0.f, 0.f, 0.f};

  const int kb0 = ks * kchunk, ke = kb0 + kchunk;
  uint4 qa0 = make_uint4(0, 0, 0, 0), qa1 = qa0, qb0, qb1;
  {
    int gr0 = m0 + sr0, gr1 = m0 + sr1;
    if (gr0 < M) qa0 = *(const uint4*)(A + (size_t)gr0 * K + kb0 + skc0);
    if (gr1 < M) qa1 = *(const uint4*)(A + (size_t)gr1 * K + kb0 + skc1);
    qb0 = *(const uint4*)(B + (size_t)(n0 + sr0) * K + kb0 + skc0);
    qb1 = *(const uint4*)(B + (size_t)(n0 + sr1) * K + kb0 + skc1);
  }

  for (int kb = kb0; kb < ke; kb += 32) {
    __syncthreads();
    *(uint4*)&Al[sr0][skc0] = qa0;
    *(uint4*)&Al[sr1][skc1] = qa1;
    *(uint4*)&Bl[sr0][skc0] = qb0;
    *(uint4*)&Bl[sr1][skc1] = qb1;
    __syncthreads();
    if (kb + 32 < ke) {
      int kn = kb + 32;
      int gr0 = m0 + sr0, gr1 = m0 + sr1;
      qa0 = make_uint4(0, 0, 0, 0); qa1 = qa0;
      if (gr0 < M) qa0 = *(const uint4*)(A + (size_t)gr0 * K + kn + skc0);
      if (gr1 < M) qa1 = *(const uint4*)(A + (size_t)gr1 * K + kn + skc1);
      qb0 = *(const uint4*)(B + (size_t)(n0 + sr0) * K + kn + skc0);
      qb1 = *(const uint4*)(B + (size_t)(n0 + sr1) * K + kn + skc1);
    }

    bf16x8 af[4], bfr[4];
#pragma unroll
    for (int rt = 0; rt < 4; ++rt)
      af[rt] = *(const bf16x8*)&Al[wr + rt * 16 + frow][fk];
#pragma unroll
    for (int ct = 0; ct < 4; ++ct)
      bfr[ct] = *(const bf16x8*)&Bl[wc + ct * 16 + frow][fk];
#pragma unroll
    for (int rt = 0; rt < 4; ++rt)
#pragma unroll
      for (int ct = 0; ct < 4; ++ct)
        acc[rt][ct] = __builtin_amdgcn_mfma_f32_16x16x32_bf16(af[rt], bfr[ct], acc[rt][ct], 0, 0, 0);
  }

#pragma unroll
  for (int rt = 0; rt < 4; ++rt) {
#pragma unroll
    for (int ct = 0; ct < 4; ++ct) {
      int col = n0 + wc + ct * 16 + (lane & 15);
#pragma unroll
      for (int reg = 0; reg < 4; ++reg) {
        int row = m0 + wr + rt * 16 + ((lane >> 4) << 2) + reg;
        if (row < M) {
          float v = acc[rt][ct][reg];
          if (STORE == 2) {
            part[((size_t)z * M + row) * cld + col] = v;
          } else {
            C[(size_t)row * cld + col] = v + ldE(bias, col, md);
          }
        }
      }
    }
  }
}

// reduce partials
template <int ACT, int ADDIN, int BIAS>
__global__ __launch_bounds__(256) void reduce_u(
    const float* __restrict__ part, int KS, int M, int ncols,
    const void* __restrict__ bias0, const void* __restrict__ bias1, long biasoff,
    float* __restrict__ C0, float* __restrict__ C1, int cld, const int* __restrict__ mode) {
  const int md = *mode;
  const int pair = blockIdx.z;
  const void* bias = pair ? bias1 : bias0;
  float* C = pair ? C1 : C0;
  size_t total = (size_t)M * ncols;
  for (size_t i = (size_t)blockIdx.x * blockDim.x + threadIdx.x; i < total;
       i += (size_t)gridDim.x * blockDim.x) {
    int row = (int)(i / ncols), col = (int)(i - (size_t)row * ncols);
    float s = ADDIN ? C[(size_t)row * cld + col] : 0.f;
    for (int ks = 0; ks < KS; ++ks)
      s += part[(((size_t)(pair * KS + ks)) * M + row) * ncols + col];
    if (BIAS) s += ldE(bias, biasoff + col, md);
    if (ACT == 1) s = fmaxf(s, 0.f);
    C[(size_t)row * cld + col] = s;
  }
}

// ============ patch-embed partial GEMM — narrow-path fallback ============
__global__ __launch_bounds__(256) void patch_part(
    const void* __restrict__ x, const void* __restrict__ w,
    float* __restrict__ part, int CPB, const int* __restrict__ mode) {
  const int md = *mode;
  __shared__ float As[25][68];
  __shared__ float Bs[25][68];
  const int m0 = blockIdx.y * 64, n0 = blockIdx.x * 64;
  const int tid = threadIdx.x;
  const int tr = tid >> 4, tc = tid & 15;
  const int z = blockIdx.z;
  float acc[4][4] = {};
  const int c0 = z * CPB;
  for (int c = c0; c < c0 + CPB; ++c) {
    __syncthreads();
    for (int e = tid; e < 1600; e += 256) {
      int p = e / 25, q = e - p * 25;
      int ki = q / 5, li = q - ki * 5;
      int n = m0 + p;
      float v = 0.f;
      if (n < NN) {
        int ni = n / NHP, nj = n - ni * NHP;
        v = ldE(x, (long)c * (HIMG * WIMG) + (5 * ni + ki) * WIMG + 5 * nj + li, md);
      }
      As[q][p] = v;
    }
    for (int e = tid; e < 1600; e += 256) {
      int o = e / 25, q = e - o * 25;
      Bs[q][o] = ldE(w, (long)(n0 + o) * 6400 + c * 25 + q, md);
    }
    __syncthreads();
#pragma unroll
    for (int kk = 0; kk < 25; ++kk) {
      float4 av = *(const float4*)&As[kk][tr * 4];
      float4 bv = *(const float4*)&Bs[kk][tc * 4];
      float a[4] = {av.x, av.y, av.z, av.w};
      float b[4] = {bv.x, bv.y, bv.z, bv.w};
#pragma unroll
      for (int i = 0; i < 4; ++i)
#pragma unroll
        for (int j = 0; j < 4; ++j) acc[i][j] = fmaf(a[i], b[j], acc[i][j]);
    }
  }
#pragma unroll
  for (int i = 0; i < 4; ++i) {
    int row = m0 + tr * 4 + i;
    if (row < NN) {
#pragma unroll
      for (int j = 0; j < 4; ++j)
        part[((size_t)z * NN + row) * 256 + n0 + tc * 4 + j] = acc[i][j];
    }
  }
}

// ===== adj: 64x64 tiled f32 GEMM, BK=32, sort arrays OVERLAID on dead staging =====
// LDS pool = max(staging 17408 B, sort 21760 B) = 21760 B; prefetch pipelined.
__global__ __launch_bounds__(256) void adj_gemm(
    const float* __restrict__ emb, float* __restrict__ pv, unsigned char* __restrict__ pi) {
  __shared__ __align__(16) char pool[21760];
  float (*As)[68] = (float(*)[68])pool;                             // [32][68] = 8704 B
  float (*Bs)[68] = (float(*)[68])(pool + 8704);                    // [32][68] = 8704 B
  float (*mv)[68] = (float(*)[68])pool;                             // [64][68] = 17408 B (overlay)
  unsigned char (*mi)[68] = (unsigned char(*)[68])(pool + 17408);   // [64][68] = 4352 B
  const int m0 = blockIdx.y * 64, n0 = blockIdx.x * 64;
  const int ct = blockIdx.x;
  const int tid = threadIdx.x;
  const int tr = tid >> 4, tc = tid & 15;
  const int ar = tid >> 2, akq = tid & 3;   // A: row ar, 8 k's at akq*8
  const int bn = tid >> 2, bkq = tid & 3;   // B: col bn, 8 k's at bkq*8
  const int arow = m0 + ar;
  const int bcol = n0 + bn;
  float acc[4][4] = {};

  float4 pa0 = make_float4(0.f, 0.f, 0.f, 0.f), pa1 = pa0, pb0 = pa0, pb1 = pa0;
  if (arow < NN) {
    const float* ap = emb + (size_t)arow * 256 + akq * 8;
    pa0 = *(const float4*)ap;
    pa1 = *(const float4*)(ap + 4);
  }
  if (bcol < NN) {
    const float* bp = emb + (size_t)bcol * 256 + bkq * 8;
    pb0 = *(const float4*)bp;
    pb1 = *(const float4*)(bp + 4);
  }

  for (int k0 = 0; k0 < 256; k0 += 32) {
    __syncthreads();
    As[akq * 8 + 0][ar] = pa0.x;
    As[akq * 8 + 1][ar] = pa0.y;
    As[akq * 8 + 2][ar] = pa0.z;
    As[akq * 8 + 3][ar] = pa0.w;
    As[akq * 8 + 4][ar] = pa1.x;
    As[akq * 8 + 5][ar] = pa1.y;
    As[akq * 8 + 6][ar] = pa1.z;
    As[akq * 8 + 7][ar] = pa1.w;
    Bs[bkq * 8 + 0][bn] = pb0.x;
    Bs[bkq * 8 + 1][bn] = pb0.y;
    Bs[bkq * 8 + 2][bn] = pb0.z;
    Bs[bkq * 8 + 3][bn] = pb0.w;
    Bs[bkq * 8 + 4][bn] = pb1.x;
    Bs[bkq * 8 + 5][bn] = pb1.y;
    Bs[bkq * 8 + 6][bn] = pb1.z;
    Bs[bkq * 8 + 7][bn] = pb1.w;
    __syncthreads();
    if (k0 + 32 < 256) {
      if (arow < NN) {
        const float* ap = emb + (size_t)arow * 256 + k0 + 32 + akq * 8;
        pa0 = *(const float4*)ap;
        pa1 = *(const float4*)(ap + 4);
      }
      if (bcol < NN) {
        const float* bp = emb + (size_t)bcol * 256 + k0 + 32 + bkq * 8;
        pb0 = *(const float4*)bp;
        pb1 = *(const float4*)(bp + 4);
      }
    }
#pragma unroll
    for (int kk = 0; kk < 32; ++kk) {
      float4 av = *(const float4*)&As[kk][tr * 4];
      float4 bv = *(const float4*)&Bs[kk][tc * 4];
      float a[4] = {av.x, av.y, av.z, av.w};
      float b[4] = {bv.x, bv.y, bv.z, bv.w};
#pragma unroll
      for (int i = 0; i < 4; ++i)
#pragma unroll
        for (int j = 0; j < 4; ++j) acc[i][j] = fmaf(a[i], b[j], acc[i][j]);
    }
  }
  __syncthreads();   // staging dead; safe to overlay mv/mi

  // per-thread sort of 4 cols per row, (val desc, idx asc)
#pragma unroll
  for (int i = 0; i < 4; ++i) {
    float v[4]; int id[4];
#pragma unroll
    for (int j = 0; j < 4; ++j) {
      int cl = tc * 4 + j;
      int valid = (n0 + cl) < NN;
      v[j] = valid ? acc[i][j] : -1e38f;
      id[j] = valid ? cl : 255;
    }
#pragma unroll
    for (int a = 1; a < 4; ++a) {
      float va = v[a]; int ia = id[a];
      int b = a;
      while (b > 0 && (va > v[b - 1] || (va == v[b - 1] && ia < id[b - 1]))) {
        v[b] = v[b - 1]; id[b] = id[b - 1]; --b;
      }
      v[b] = va; id[b] = ia;
    }
    int rl = tr * 4 + i;
#pragma unroll
    for (int s = 0; s < 4; ++s) {
      mv[rl][tc * 4 + s] = v[s];
      mi[rl][tc * 4 + s] = (unsigned char)id[s];
    }
  }
  __syncthreads();

  // one thread per row (64): merge 16 sorted 4-lists -> sorted top-7 for this col tile
  if (tid < 64) {
    int row = m0 + tid;
    if (row < NN) {
      int ptr[16];
#pragma unroll
      for (int g = 0; g < 16; ++g) ptr[g] = 0;
      for (int k = 0; k < 7; ++k) {
        float best = -1e38f; int bid = 0x7fffffff; int bg = 0;
        for (int g = 0; g < 16; ++g) {
          if (ptr[g] < 4) {
            float vv = mv[tid][g * 4 + ptr[g]];
            int ii = mi[tid][g * 4 + ptr[g]];
            if (vv > best || (vv == best && ii < bid)) { best = vv; bid = ii; bg = g; }
          }
        }
        ptr[bg]++;
        pv[(size_t)row * (NCT * 7) + ct * 7 + k] = best;
        pi[(size_t)row * (NCT * 7) + ct * 7 + k] = (unsigned char)bid;
      }
    }
  }
}

// wave-parallel merge: one wave per row, lane c = list c head; 7x butterfly argmax (exact)
__global__ __launch_bounds__(256) void adj_merge57(
    const float* __restrict__ pv, const unsigned char* __restrict__ pi,
    int* __restrict__ idx_o, int* __restrict__ keep_o) {
  const int wid = threadIdx.x >> 6, lane = threadIdx.x & 63;
  const int row = blockIdx.x * 4 + wid;
  if (row >= NN) return;
  const size_t base = (size_t)row * (NCT * 7);
  int p = 0;
  float mval = -1e38f;
  int mid = 0x7fffffff;
  if (lane < NCT) {
    mval = pv[base + lane * 7];
    mid = lane * 64 + (int)pi[base + lane * 7];
  }
  for (int k = 0; k < 7; ++k) {
    float v = mval; int i = mid;
#pragma unroll
    for (int off = 32; off > 0; off >>= 1) {
      float ov = __shfl_xor(v, off, 64);
      int oi = __shfl_xor(i, off, 64);
      if (ov > v || (ov == v && oi < i)) { v = ov; i = oi; }
    }
    if (lane == 0) {
      idx_o[row * 7 + k] = i;
      keep_o[row * 7 + k] = (i > row && v != 0.0f) ? 1 : 0;
    }
    if (mval == v && mid == i) {
      ++p;
      if (p < 7) {
        mval = pv[base + lane * 7 + p];
        mid = lane * 64 + (int)pi[base + lane * 7 + p];
      } else {
        mval = -1e38f; mid = 0x7fffffff;
      }
    }
  }
}

// ---------------- spatial kNN via 5x5 window ----------------
__global__ __launch_bounds__(256) void spatial_topk(int* __restrict__ idx_o, int* __restrict__ keep_o) {
  int r = blockIdx.x * 256 + threadIdx.x;
  if (r >= NN) return;
  int ri = r / NHP, rj = r - (r / NHP) * NHP;
  int bd[7], bi[7];
#pragma unroll
  for (int k = 0; k < 7; ++k) { bd[k] = 0x7fffffff; bi[k] = 0x7fffffff; }
  int ilo = ri - 2 > 0 ? ri - 2 : 0, ihi = ri + 2 < NHP - 1 ? ri + 2 : NHP - 1;
  int jlo = rj - 2 > 0 ? rj - 2 : 0, jhi = rj + 2 < NHP - 1 ? rj + 2 : NHP - 1;
  for (int i2 = ilo; i2 <= ihi; ++i2) {
    int dy = ri - i2; int dy2 = dy * dy;
    for (int j2 = jlo; j2 <= jhi; ++j2) {
      int dx = rj - j2;
      int d = dy2 + dx * dx;
      int m = i2 * NHP + j2;
      if (d < bd[6]) {
        int pq = 6;
        while (pq > 0 && d < bd[pq - 1]) { bd[pq] = bd[pq - 1]; bi[pq] = bi[pq - 1]; --pq; }
        bd[pq] = d; bi[pq] = m;
      }
    }
  }
#pragma unroll
  for (int k = 0; k < 7; ++k) {
    idx_o[r * 7 + k] = bi[k];
    keep_o[r * 7 + k] = (bi[k] >= r && bd[k] != 0) ? 1 : 0;
  }
}

// ---------------- GATv2 aggregation, single head (stride 256, f32 out) ----------------
__global__ __launch_bounds__(256) void gat_agg1(
    const float* __restrict__ xl, const float* __restrict__ xr,
    const void* __restrict__ att, long attoff, const void* __restrict__ gbias, long gboff,
    const int* __restrict__ nbr, const int* __restrict__ keep,
    float* __restrict__ out, const int* __restrict__ mode) {
  const int md = *mode;
  const int r = blockIdx.x;
  const int f = threadIdx.x;
  __shared__ int s_src[8];
  __shared__ int s_mask_s;
  __shared__ float red[4][8];
  if (f < 7) {
    int v = nbr[r * 7 + f];
    s_src[f] = ((unsigned)v < (unsigned)NN) ? v : 0;
  }
  if (f == 7) s_src[7] = r;
  if (f == 0) {
    int mk = 0x80;
    for (int e = 0; e < 7; ++e)
      if (keep[r * 7 + e] != 0) mk |= (1 << e);
    s_mask_s = mk;
  }
  __syncthreads();
  const int mask = s_mask_s;
  const int wid = f >> 6, lane = f & 63;

  float xrv = xr[(size_t)r * 256 + f];
  float attv = ldE(att, attoff + f, md);
  float xlv[8], part[8];
#pragma unroll
  for (int e = 0; e < 8; ++e) {
    xlv[e] = 0.f; part[e] = 0.f;
    if (mask & (1 << e)) {
      float v = xl[(size_t)s_src[e] * 256 + f];
      xlv[e] = v;
      float s = v + xrv;
      s = s > 0.f ? s : 0.2f * s;
      part[e] = s * attv;
    }
  }
#pragma unroll
  for (int e = 0; e < 8; ++e) {
    float v = part[e];
#pragma unroll
    for (int off = 32; off > 0; off >>= 1) v += __shfl_xor(v, off, 64);
    if (lane == 0) red[wid][e] = v;
  }
  __syncthreads();
  float m = -1e38f;
  float logit[8];
#pragma unroll
  for (int e = 0; e < 8; ++e) {
    logit[e] = red[0][e] + red[1][e] + red[2][e] + red[3][e];
    if (mask & (1 << e)) m = fmaxf(m, logit[e]);
  }
  float den = 0.f, al[8];
#pragma unroll
  for (int e = 0; e < 8; ++e) {
    al[e] = (mask & (1 << e)) ? expf(logit[e] - m) : 0.f;
    den += al[e];
  }
  float inv = 1.0f / den;
  float o = 0.f;
#pragma unroll
  for (int e = 0; e < 8; ++e) o = fmaf(al[e], xlv[e], o);
  o = o * inv + ldE(gbias, gboff + f, md);
  o = o > 0.f ? o : expm1f(o);
  out[(size_t)r * 256 + f] = o;
}

// ------- GATv2 aggregation, per-(node, head) grid (stride 2048), bf16 output -------
__global__ __launch_bounds__(256) void gat_agg8h(
    const float* __restrict__ xl, const float* __restrict__ xr,
    const void* __restrict__ att, const void* __restrict__ gbias,
    const int* __restrict__ nbr, const int* __restrict__ keep,
    unsigned short* __restrict__ out, const int* __restrict__ mode) {
  const int md = *mode;
  const int r = blockIdx.x;
  const int h = blockIdx.y;
  const int f = threadIdx.x;
  __shared__ int s_src[8];
  __shared__ int s_mask_s;
  __shared__ float red[4][8];
  if (f < 7) {
    int v = nbr[r * 7 + f];
    s_src[f] = ((unsigned)v < (unsigned)NN) ? v : 0;
  }
  if (f == 7) s_src[7] = r;
  if (f == 0) {
    int mk = 0x80;
    for (int e = 0; e < 7; ++e)
      if (keep[r * 7 + e] != 0) mk |= (1 << e);
    s_mask_s = mk;
  }
  __syncthreads();
  const int mask = s_mask_s;
  const int wid = f >> 6, lane = f & 63;

  float xrv = xr[(size_t)r * 2048 + h * 256 + f];
  float attv = ldE(att, h * 256 + f, md);
  float xlv[8], part[8];
#pragma unroll
  for (int e = 0; e < 8; ++e) {
    xlv[e] = 0.f; part[e] = 0.f;
    if (mask & (1 << e)) {
      float v = xl[(size_t)s_src[e] * 2048 + h * 256 + f];
      xlv[e] = v;
      float s = v + xrv;
      s = s > 0.f ? s : 0.2f * s;
      part[e] = s * attv;
    }
  }
#pragma unroll
  for (int e = 0; e < 8; ++e) {
    float v = part[e];
#pragma unroll
    for (int off = 32; off > 0; off >>= 1) v += __shfl_xor(v, off, 64);
    if (lane == 0) red[wid][e] = v;
  }
  __syncthreads();
  float m = -1e38f;
  float logit[8];
#pragma unroll
  for (int e = 0; e < 8; ++e) {
    logit[e] = red[0][e] + red[1][e] + red[2][e] + red[3][e];
    if (mask & (1 << e)) m = fmaxf(m, logit[e]);
  }
  float den = 0.f, al[8];
#pragma unroll
  for (int e = 0; e < 8; ++e) {
    al[e] = (mask & (1 << e)) ? expf(logit[e] - m) : 0.f;
    den += al[e];
  }
  float inv = 1.0f / den;
  float o = 0.f;
#pragma unroll
  for (int e = 0; e < 8; ++e) o = fmaf(al[e], xlv[e], o);
  o = o * inv + ldE(gbias, h * 256 + f, md);
  o = o > 0.f ? o : expm1f(o);
  out[(size_t)r * 2048 + h * 256 + f] = f2bf(o);
}

// ---------------- final: out = relu(cat(h2,h4)@fc3 + b) + h4 ----------------
__global__ __launch_bounds__(256) void fc3_final(
    const float* __restrict__ h2, const float* __restrict__ h4,
    const void* __restrict__ B, const void* __restrict__ bias,
    void* __restrict__ outp, const int* __restrict__ mode) {
  const int md = *mode;
  __shared__ float As[16][68];
  __shared__ float Bs[16][68];
  const int m0 = blockIdx.y * 64, n0 = blockIdx.x * 64;
  const int tid = threadIdx.x;
  const int tr = tid >> 4, tc = tid & 15;
  const int ar = tid >> 2, akq = tid & 3;
  const int bkr = tid >> 4, bnc = tid & 15;
  const int arow = m0 + ar;
  float acc[4][4] = {};

  for (int k0 = 0; k0 < 512; k0 += 16) {
    __syncthreads();
    {
      int k = k0 + akq * 4;
      float4 v = make_float4(0.f, 0.f, 0.f, 0.f);
      if (arow < NN) {
        const float* src = (k < 256) ? (h2 + (size_t)arow * 256 + k)
                                     : (h4 + (size_t)arow * 256 + (k - 256));
        v = *(const float4*)src;
      }
      As[akq * 4 + 0][ar] = v.x;
      As[akq * 4 + 1][ar] = v.y;
      As[akq * 4 + 2][ar] = v.z;
      As[akq * 4 + 3][ar] = v.w;
    }
    {
      long bidx = (long)(k0 + bkr) * 256 + n0 + bnc * 4;
      if (md) {
        ushort4 u = *(const ushort4*)((const unsigned short*)B + bidx);
        Bs[bkr][bnc * 4 + 0] = bf2f(u.x);
        Bs[bkr][bnc * 4 + 1] = bf2f(u.y);
        Bs[bkr][bnc * 4 + 2] = bf2f(u.z);
        Bs[bkr][bnc * 4 + 3] = bf2f(u.w);
      } else {
        float4 v = *(const float4*)((const float*)B + bidx);
        Bs[bkr][bnc * 4 + 0] = v.x;
        Bs[bkr][bnc * 4 + 1] = v.y;
        Bs[bkr][bnc * 4 + 2] = v.z;
        Bs[bkr][bnc * 4 + 3] = v.w;
      }
    }
    __syncthreads();
#pragma unroll
    for (int kk = 0; kk < 16; ++kk) {
      float4 av = *(const float4*)&As[kk][tr * 4];
      float4 bv = *(const float4*)&Bs[kk][tc * 4];
      float a[4] = {av.x, av.y, av.z, av.w};
      float b[4] = {bv.x, bv.y, bv.z, bv.w};
#pragma unroll
      for (int i = 0; i < 4; ++i)
#pragma unroll
        for (int j = 0; j < 4; ++j) acc[i][j] = fmaf(a[i], b[j], acc[i][j]);
    }
  }
#pragma unroll
  for (int i = 0; i < 4; ++i) {
    int row = m0 + tr * 4 + i;
    if (row < NN) {
#pragma unroll
      for (int j = 0; j < 4; ++j) {
        int col = n0 + tc * 4 + j;
        float v = fmaxf(acc[i][j] + ldE(bias, col, md), 0.f) + h4[(size_t)row * 256 + col];
        if (md) ((__hip_bfloat16*)outp)[(size_t)row * 256 + col] = __float2bfloat16(v);
        else ((float*)outp)[(size_t)row * 256 + col] = v;
      }
    }
  }
}

// ---------------- launcher ----------------
extern "C" void kernel_launch(void* const* d_in, const int* in_sizes, int n_in,
                              void* d_out, int out_size, void* d_ws, size_t ws_size,
                              hipStream_t stream) {
  (void)in_sizes; (void)n_in; (void)out_size;
  const void* x    = d_in[0];
  const void* w1   = d_in[1];
  const void* b1   = d_in[2];
  const void* fc2w = d_in[3];
  const void* fc2b = d_in[4];
  const void* fc3w = d_in[5];
  const void* fc3b = d_in[6];
  const void* g_wl[4]   = {d_in[7],  d_in[13], d_in[19], d_in[25]};
  const void* g_bl[4]   = {d_in[8],  d_in[14], d_in[20], d_in[26]};
  const void* g_wr[4]   = {d_in[9],  d_in[15], d_in[21], d_in[27]};
  const void* g_br[4]   = {d_in[10], d_in[16], d_in[22], d_in[28]};
  const void* g_att[4]  = {d_in[11], d_in[17], d_in[23], d_in[29]};
  const void* g_bias[4] = {d_in[12], d_in[18], d_in[24], d_in[30]};

  float* ws = (float*)d_ws;
  int* mode = (int*)d_ws;
  size_t off = 64;
  float* emb = ws + off; off += (size_t)NN * 256;
  float* xl2 = ws + off; off += (size_t)NN * 256;
  float* xr2 = ws + off; off += (size_t)NN * 256;
  float* h2  = ws + off; off += (size_t)NN * 256;
  float* h4  = ws + off; off += (size_t)NN * 256;
  int* idx1  = (int*)(ws + off); off += NN * 7;
  int* keep1 = (int*)(ws + off); off += NN * 7;
  int* idx2  = (int*)(ws + off); off += NN * 7;
  int* keep2 = (int*)(ws + off); off += NN * 7;
  unsigned short* emb_bf = (unsigned short*)(ws + off); off += (size_t)NN * 256 / 2;
  unsigned short* wbfL   = (unsigned short*)(ws + off); off += (size_t)524288 / 2;
  unsigned short* wbfR   = (unsigned short*)(ws + off); off += (size_t)524288 / 2;
  float* scratch = ws + off;
  const size_t wide_need = off + 3 * (size_t)NN * 2048;          // ~111.3 MB
  const bool wide = ws_size >= wide_need * sizeof(float);

  float* emb1 = h2;            // conv output; dead before h2 is written
  float* pv = scratch;         // adj scratch (after conv partials die)
  unsigned char* pi = (unsigned char*)(scratch + (size_t)NN * (NCT * 7));

  dim3 blk(256);
  const int* idxs[2]  = {idx1, idx2};
  const int* keeps[2] = {keep1, keep2};
  float* houts[2] = {h2, h4};
  const int* f32mode = mode + 1;

  detect_mode<<<dim3(1), blk, 0, stream>>>((const unsigned short*)x, mode);

  if (wide) {
    // conv via im2col halves + K-split f32 GEMM (pipelined 128x64, 8 chunks/half)
    float* wT   = scratch;
    float* part = wT + (size_t)6400 * 256;
    float* a2   = part + 8 * (size_t)NN * 256;

    wtrans<<<dim3(200, 8), blk, 0, stream>>>(w1, wT, mode);
    for (int h = 0; h < 2; ++h) {
      im2col<<<dim3(2048), blk, 0, stream>>>(x, a2, h, mode);
      gemm_f84<<<dim3(4, 29, 8), blk, 0, stream>>>(a2, wT, (long)h * 3200 * 256,
                                                   part, NN, 3200, 400, 256);
      if (h == 0)
        reduce_u<0, 0, 0><<<dim3(1024, 1, 1), blk, 0, stream>>>(part, 8, NN, 256,
                                                                b1, b1, 0, emb1, emb1, 256, mode);
      else
        reduce_u<1, 1, 1><<<dim3(1024, 1, 1), blk, 0, stream>>>(part, 8, NN, 256,
                                                                b1, b1, 0, emb1, emb1, 256, mode);
    }
  } else {
    const int convKS = 2;
    patch_part<<<dim3(4, 57, convKS), blk, 0, stream>>>(x, w1, scratch, 256 / convKS, mode);
    reduce_u<1, 0, 1><<<dim3(1024, 1, 1), blk, 0, stream>>>(scratch, convKS, NN, 256,
                                                            b1, b1, 0, emb1, emb1, 256, mode);
  }

  // fc2 -> emb (f32)
  gemm_u<0, 1><<<dim3(4, 57, 1), blk, 0, stream>>>(emb1, fc2w, fc2w, 0, fc2b, fc2b, 0,
                                                   emb, emb, nullptr, 256,
                                                   NN, 256, 256, 1, 256, mode);
  // graphs (f32, exact)
  adj_gemm<<<dim3(NCT, NCT), blk, 0, stream>>>(emb, pv, pi);
  adj_merge57<<<dim3(900), blk, 0, stream>>>(pv, pi, idx1, keep1);
  spatial_topk<<<dim3(15), blk, 0, stream>>>(idx2, keep2);

  if (wide) {
    float* xl_w = scratch;
    float* xr_w = xl_w + (size_t)NN * 2048;
    float* hh_w = xr_w + (size_t)NN * 2048;
    unsigned short* hh_bf = (unsigned short*)hh_w;   // gat_agg8h writes bf16 here directly
    float* g24part = xr_w;                           // aliases xr_w (dead after gat_agg8h)

    cvt_bf16<<<dim3(512), blk, 0, stream>>>(emb, emb_bf, (long)NN * 64);

    for (int g = 0; g < 2; ++g) {
      int a = g * 2, b = g * 2 + 1;
      wconvT2<<<dim3(8, 64, 2), blk, 0, stream>>>(g_wl[a], g_wr[a], wbfL, wbfR, 256, 2048, mode);
      gemm_mf<0><<<dim3(16, 29, 2), blk, 0, stream>>>(emb_bf, wbfL, wbfR,
                                                      g_bl[a], g_br[a],
                                                      xl_w, xr_w, nullptr, 2048,
                                                      NN, 256, 256, 1, mode);
      gat_agg8h<<<dim3(NN, 8), blk, 0, stream>>>(xl_w, xr_w, g_att[a], g_bias[a],
                                                 idxs[g], keeps[g], hh_bf, mode);
      wconvT2<<<dim3(64, 8, 2), blk, 0, stream>>>(g_wl[b], g_wr[b], wbfL, wbfR, 2048, 256, mode);
      gemm_mf<2><<<dim3(2, 29, 8), blk, 0, stream>>>(hh_bf, wbfL, wbfR,
                                                     nullptr, nullptr,
                                                     nullptr, nullptr, g24part, 256,
                                                     NN, 2048, 512, 4, mode);
      reduce_u<0, 0, 1><<<dim3(1024, 1, 2), blk, 0, stream>>>(g24part, 4, NN, 256,
                                                              g_bl[b], g_br[b], 0,
                                                              xl2, xr2, 256, mode);
      gat_agg1<<<dim3(NN), blk, 0, stream>>>(xl2, xr2, g_att[b], 0, g_bias[b], 0,
                                             idxs[g], keeps[g], houts[g], mode);
    }
  } else {
    float* xlh = scratch;
    float* xrh = xlh + (size_t)NN * 256;
    float* hh  = xrh + (size_t)NN * 256;

    for (int g = 0; g < 2; ++g) {
      int a = g * 2, b = g * 2 + 1;
      for (int h = 0; h < 8; ++h) {
        gemm_u<0, 0><<<dim3(4, 57, 2), blk, 0, stream>>>(emb, g_wl[a], g_wr[a], h * 256,
                                                         g_bl[a], g_br[a], h * 256,
                                                         xlh, xrh, nullptr, 256,
                                                         NN, 256, 256, 1, 2048, mode);
        gat_agg1<<<dim3(NN), blk, 0, stream>>>(xlh, xrh, g_att[a], h * 256, g_bias[a], h * 256,
                                               idxs[g], keeps[g], hh, mode);
        if (h == 0) {
          gemm_u<0, 0><<<dim3(4, 57, 2), blk, 0, stream>>>(hh, g_wl[b], g_wr[b], 0,
                                                           g_bl[b], g_br[b], 0,
                                                           xl2, xr2, nullptr, 256,
                                                           NN, 256, 256, 1, 256, mode);
        } else {
          gemm_u<1, 0><<<dim3(4, 57, 2), blk, 0, stream>>>(hh, g_wl[b], g_wr[b], (long)h * 256 * 256,
                                                           g_bl[b], g_br[b], 0,
                                                           xl2, xr2, nullptr, 256,
                                                           NN, 256, 256, 1, 256, mode);
        }
      }
      gat_agg1<<<dim3(NN), blk, 0, stream>>>(xl2, xr2, g_att[b], 0, g_bias[b], 0,
                                             idxs[g], keeps[g], houts[g], mode);
    }
  }

  fc3_final<<<dim3(4, 57), blk, 0, stream>>>(h2, h4, fc3w, fc3b, d_out, mode);
}